// Round 10
// baseline (2743.497 us; speedup 1.0000x reference)
//
#include <hip/hip_runtime.h>
#include <cstddef>

// SimpleLSTM: B=64, D=512, T=512, H=1024, O=1 — fp16, tagged h-packets (r6 base,
// 1857.7us verified) + x-PREFETCH (1-step software pipeline) + DOUBLE-GENERATION
// pipelined packet retry.
// MODEL (r2-r8): time = 512 x serial coherence chain. r6 counters: MFMA 6% +
// VALU 11% => ~83% VMEM wait. Two serial wait terms addressed here, protocol
// untouched: (1) xT streaming load consumed immediately by the pinned x-MFMAs
// => ~1-2k cyc HBM stall at top of every step -> prefetch t+1 into regs during
// step t; (2) retry loop samples at full-RTT granularity -> two staggered
// 16-word generations halve the sample period (worst-case codegen == r6).
// r8 lesson: 32-j blocks spill weights (192 VGPR invariant) — reverted to r6's
// 4 groups x 64 blocks x 16 batches (16 j/block, 96 weight VGPRs).
// ws layout (ends at 46,661,632):
//   [0, 32MB)            xT: f16 [T=512][B=64][D=512]
//   [32MB, +12.58MB)     Wf: f16 A-frags [r=64][ks=48][mt=4][lane=64][8]
//                        (reused after weight load as out-partials
//                         part[t=512][g=4][r=64][b16=16] f32 = 8MB, atomicAdd'd)
//   [46,137,344, +512KB) pkt[parity=2][g=4][r=64][mt=4][b=16] x 16B packets
//                        packet = {h0,h1,h2,tagA | h3,tagB,pad,pad} (2 u64)
//                        claim/ready ctrs overlay first ~1KB of parity-1 region
//                        (stale bits read as tag 0 != expected -> retry, safe).
#define WS_XT_OFF   0ull
#define WS_WF_OFF   33554432ull
#define WS_PK_OFF   46137344ull

typedef _Float16 f16x8 __attribute__((ext_vector_type(8)));
typedef float    f32x4 __attribute__((ext_vector_type(4)));
typedef unsigned short u16;
typedef unsigned int   u32;
typedef unsigned long long u64;

__device__ __forceinline__ u16 f2h(float f) {
  _Float16 h = (_Float16)f;                     // v_cvt_f16_f32, RNE
  return __builtin_bit_cast(u16, h);
}
// Fast gate math: v_exp + v_rcp. Robust at extremes.
__device__ __forceinline__ float sigm(float x) {
  return __builtin_amdgcn_rcpf(1.0f + __expf(-x));
}
__device__ __forceinline__ float tanh_fast(float x) {
  return 1.0f - 2.0f * __builtin_amdgcn_rcpf(__expf(2.0f * x) + 1.0f);
}

// ---------- K0: zero packet region (tags=0 == step-0 expectation, h=0) ----------
__global__ __launch_bounds__(256) void k_init(uint4* pkt16) {
  int t = blockIdx.x * 256 + threadIdx.x;       // 32768 threads x 16B = 512KB exact
  pkt16[t] = uint4{0u, 0u, 0u, 0u};
}

// ---------- K1: x (B,D,T) f32 -> xT[t][b][d] f16 ----------
__global__ __launch_bounds__(256) void k_xpose(const float* __restrict__ x,
                                               u16* __restrict__ xT) {
  __shared__ float lds[64][65];
  const int d0 = blockIdx.x * 64, t0 = blockIdx.y * 64, b = blockIdx.z;
  const int tid = threadIdx.x;
  const int tt = tid & 63, dr = tid >> 6;
  const float* xp = x + ((size_t)b * 512 + d0) * 512 + t0 + tt;
#pragma unroll
  for (int i = 0; i < 16; ++i) {
    int dd = i * 4 + dr;
    lds[dd][tt] = xp[(size_t)dd * 512];
  }
  __syncthreads();
  const int dp = tid & 31, rr = tid >> 5;
#pragma unroll
  for (int i = 0; i < 8; ++i) {
    int tt2 = i * 8 + rr;
    u32 lo = f2h(lds[dp * 2][tt2]);
    u32 hi = f2h(lds[dp * 2 + 1][tt2]);
    *(u32*)(xT + ((size_t)(t0 + tt2) * 64 + b) * 512 + d0 + dp * 2) = lo | (hi << 16);
  }
}

// ---------- K2: pack [W_ih | W_hh] rows into per-lane MFMA A-fragments (f16) ----------
// chunk c = (r*48 + ks)*4 + mt ; within-tile row m: gate=m&3, j=r*16+mt*4+(m>>2)
__global__ __launch_bounds__(256) void k_wfrag(const float* __restrict__ W_ih,
                                               const float* __restrict__ W_hh,
                                               u16* __restrict__ Wf) {
  int g = blockIdx.x * 256 + threadIdx.x;       // 786432 threads
  int lane = g & 63;
  int c  = g >> 6;                              // [0, 12288)
  int mt = c & 3;
  int cc = c >> 2;
  int ks = cc % 48;
  int r  = cc / 48;
  int m = lane & 15, q = lane >> 4;
  int gate = m & 3;
  int j = r * 16 + mt * 4 + (m >> 2);
  int row = gate * 1024 + j;
  const float* src = (ks < 16) ? (W_ih + (size_t)row * 512 + ks * 32 + q * 8)
                               : (W_hh + (size_t)row * 1024 + (ks - 16) * 32 + q * 8);
  union { u16 s[8]; uint4 v; } U;
#pragma unroll
  for (int i = 0; i < 8; ++i) U.s[i] = f2h(src[i]);
  *(uint4*)(Wf + ((size_t)c * 64 + lane) * 8) = U.v;
}

// ---------- K3: persistent cooperative recurrence ----------
// grid 256 = 4 groups x 64 blocks; block 512 = 8 waves; 1 block/CU.
// XCD CLAIM (r4/r8 counter-verified): g = xcd>>1, r = (xcd&1)|(slot<<1) —
// localizes each group onto 2 XCDs (FETCH halved).
// PACKETS (r6, measured-good): producer reducer-wave mt gathers 4 q-values per
// batch (2 shfl_xor) and fires TWO u64 agent stores per lane<16:
// {h0,h1,h2,tagA | h3,tagB} at pkt[(t+1)&1][g][r][mt][b]. Consumer wave w
// retry-loads its 16 u64 and validates embedded tags == t; poll IS data load.
__global__ __launch_bounds__(512, 2) void k_lstm(
    const u16* __restrict__ xT, const u16* __restrict__ Wf,
    u64* pkt,
    const float* __restrict__ b_ih, const float* __restrict__ b_hh,
    const float* __restrict__ W_out, float* __restrict__ part) {
  __shared__ f32x4 red[2][8 * 4 * 64];    // [parity][wave][mt][lane], 64 KB
  __shared__ u32 sh_as;                   // claimed (xcd<<8)|slot
  const int tid = threadIdx.x;
  const int w = tid >> 6, lane = tid & 63;

  // claim/ready overlay in parity-1 region (stale bits read as tag 0 -> safe)
  u32* cc = (u32*)(pkt + 32768);

  if (tid == 0) {
    u32 xcc;
    asm volatile("s_getreg_b32 %0, hwreg(HW_REG_XCC_ID)" : "=s"(xcc));
    xcc &= 7u;
    u32 sel = 0u, slot = 0u;
    for (int i = 0; i < 8; ++i) {
      u32 x = (xcc + (u32)i) & 7u;
      u32 s = __hip_atomic_fetch_add(cc + x * 32, 1u,
                                     __ATOMIC_RELAXED, __HIP_MEMORY_SCOPE_AGENT);
      if (s < 32u) { sel = x; slot = s; break; }
    }
    sh_as = (sel << 8) | slot;
  }
  __syncthreads();
  const u32 as = sh_as;
  const int g = (int)((as >> 8) >> 1);
  const int r = (int)(((as >> 8) & 1u) | ((as & 255u) << 1));
  const int bg0 = g * 16, j0 = r * 16;
  const int n = lane & 15, q = lane >> 4;

  // Step-invariant weights -> registers
  f16x8 wfr[6][4];
#pragma unroll
  for (int kl = 0; kl < 6; ++kl) {
    int ks = (kl < 2) ? (2 * w + kl) : (16 + 4 * w + (kl - 2));
#pragma unroll
    for (int mt = 0; mt < 4; ++mt) {
      size_t c = ((size_t)r * 48 + ks) * 4 + mt;
      wfr[kl][mt] = *(const f16x8*)(Wf + (c * 64 + lane) * 8);
    }
  }

  float bias0 = 0.f, bias1 = 0.f, bias2 = 0.f, bias3 = 0.f, wout = 0.f;
  if (w < 4) {
    int j = j0 + w * 4 + q;
    bias0 = b_ih[j]        + b_hh[j];
    bias1 = b_ih[1024 + j] + b_hh[1024 + j];
    bias2 = b_ih[2048 + j] + b_hh[2048 + j];
    bias3 = b_ih[3072 + j] + b_hh[3072 + j];
    wout  = W_out[j];
  }

  // Consumer packet bases (u64 units within a parity), layout [g][p][mt][b]:
  // idx = (((g*64 + p)*4 + mt')*16 + n)*2 ; p=(4w+kl)*2+(q>>1), mt'=(q&1)*2.
  size_t cb[4];
#pragma unroll
  for (int kl = 0; kl < 4; ++kl) {
    int p = (4 * w + kl) * 2 + (q >> 1);
    cb[kl] = ((((size_t)g * 64 + p) * 4 + (size_t)((q & 1) * 2)) * 16 + n) * 2;
  }
  // Producer packet base (w<4, lane<16): block r, quarter mt=w, batch b=lane
  const size_t pwb = ((((size_t)g * 64 + r) * 4 + w) * 16 + (lane & 15)) * 2;

  // One-time grid barrier: all Wf loads done before part[] overwrites Wf.
  __syncthreads();                        // drains vmcnt -> wfr in regs
  if (tid == 0) {
    __hip_atomic_fetch_add(cc + 256, 1u, __ATOMIC_RELAXED, __HIP_MEMORY_SCOPE_AGENT);
    while (__hip_atomic_load(cc + 256, __ATOMIC_RELAXED, __HIP_MEMORY_SCOPE_AGENT) < 256u)
      __builtin_amdgcn_s_sleep(8);
  }
  __syncthreads();
  // zero own out-partial slice part[t=tid][g][r][0..16)
  {
    f32x4 z = {0.f, 0.f, 0.f, 0.f};
    f32x4* p4 = (f32x4*)&part[((size_t)(tid * 4 + g) * 64 + r) * 16];
    p4[0] = z; p4[1] = z; p4[2] = z; p4[3] = z;
  }
  __syncthreads();                        // drain zero stores before any atomicAdd
  asm volatile("" ::: "memory");

  float c_state = 0.f;
  const f32x4 zero = {0.f, 0.f, 0.f, 0.f};

  // x-prefetch registers: step-0 x loaded in prologue (one-time serial cost)
  const int xoff = (bg0 + n) * 512 + q * 8;
  f16x8 xpf0 = *(const f16x8*)(xT + xoff + (2 * w + 0) * 32);
  f16x8 xpf1 = *(const f16x8*)(xT + xoff + (2 * w + 1) * 32);

  for (int t = 0; t < 512; ++t) {
    // consume prefetched x (loads issued a full step ago -> vmcnt wait ~0)
    f16x8 bfr[6];
    bfr[0] = xpf0;
    bfr[1] = xpf1;
    // issue prefetch for t+1 (wraps to 0 at the end: valid address, unused)
    {
      const u16* xtn = xT + (size_t)((t + 1) & 511) * 32768;
      xpf0 = *(const f16x8*)(xtn + xoff + (2 * w + 0) * 32);
      xpf1 = *(const f16x8*)(xtn + xoff + (2 * w + 1) * 32);
    }

    // x-part MFMAs BEFORE the packet wait (x already in regs; ~issue cost only)
    f32x4 acc[4];
#pragma unroll
    for (int mt = 0; mt < 4; ++mt)
      acc[mt] = __builtin_amdgcn_mfma_f32_16x16x32_f16(wfr[0][mt], bfr[0], zero, 0, 0, 0);
#pragma unroll
    for (int mt = 0; mt < 4; ++mt)
      acc[mt] = __builtin_amdgcn_mfma_f32_16x16x32_f16(wfr[1][mt], bfr[1], acc[mt], 0, 0, 0);
#pragma unroll
    for (int mt = 0; mt < 4; ++mt) asm volatile("" : "+v"(acc[mt]));

    // --- double-generation pipelined validated packet load ---
    // Two staggered 16-word samples: issue B, check A; issue A, check B.
    // Halves detection lag after last-producer publish; worst-case codegen
    // (conservative vmcnt(0)) degrades to the r6 single-generation loop.
    u64 A[16], Bg[16];
    {
      const u64* pb = pkt + (size_t)(t & 1) * 32768;
      const u32 et = (u32)t;
#define PKT_ISSUE(S)                                                           \
      _Pragma("unroll")                                                        \
      for (int kl = 0; kl < 4; ++kl) {                                         \
        const u64* p = pb + cb[kl];                                            \
        S[kl*4+0] = __hip_atomic_load(p,      __ATOMIC_RELAXED, __HIP_MEMORY_SCOPE_AGENT); \
        S[kl*4+1] = __hip_atomic_load(p + 1,  __ATOMIC_RELAXED, __HIP_MEMORY_SCOPE_AGENT); \
        S[kl*4+2] = __hip_atomic_load(p + 32, __ATOMIC_RELAXED, __HIP_MEMORY_SCOPE_AGENT); \
        S[kl*4+3] = __hip_atomic_load(p + 33, __ATOMIC_RELAXED, __HIP_MEMORY_SCOPE_AGENT); \
      }
#define PKT_OK(S, okv)                                                         \
      okv = true;                                                              \
      _Pragma("unroll")                                                        \
      for (int kl = 0; kl < 4; ++kl) {                                         \
        okv = okv & ((u32)(S[kl*4+0] >> 48) == et)                             \
                  & (((u32)(S[kl*4+1] >> 16) & 0xffffu) == et)                 \
                  & ((u32)(S[kl*4+2] >> 48) == et)                             \
                  & (((u32)(S[kl*4+3] >> 16) & 0xffffu) == et);                \
      }
      PKT_ISSUE(A);
      for (;;) {
        PKT_ISSUE(Bg);
        bool okA; PKT_OK(A, okA);
        if (__all((int)okA)) break;
        PKT_ISSUE(A);
        bool okB; PKT_OK(Bg, okB);
        if (__all((int)okB)) {
#pragma unroll
          for (int i = 0; i < 16; ++i) A[i] = Bg[i];
          break;
        }
      }
#undef PKT_ISSUE
#undef PKT_OK
    }
    asm volatile("" ::: "memory");

    // assemble h fragments from validated packets (set A)
#pragma unroll
    for (int kl = 0; kl < 4; ++kl) {
      union { u32 u[4]; f16x8 v; } Bu;
      Bu.u[0] = (u32)A[kl*4+0];
      Bu.u[1] = ((u32)(A[kl*4+0] >> 32) & 0xffffu) | (((u32)A[kl*4+1] & 0xffffu) << 16);
      Bu.u[2] = (u32)A[kl*4+2];
      Bu.u[3] = ((u32)(A[kl*4+2] >> 32) & 0xffffu) | (((u32)A[kl*4+3] & 0xffffu) << 16);
      bfr[kl + 2] = Bu.v;
    }

#pragma unroll
    for (int kl = 2; kl < 6; ++kl)
#pragma unroll
      for (int mt = 0; mt < 4; ++mt)
        acc[mt] = __builtin_amdgcn_mfma_f32_16x16x32_f16(wfr[kl][mt], bfr[kl], acc[mt], 0, 0, 0);

#pragma unroll
    for (int mt = 0; mt < 4; ++mt)
      red[t & 1][(w * 4 + mt) * 64 + lane] = acc[mt];
    __syncthreads();                      // the ONLY barrier per step

    if (w < 4) {
      const int mt = w;
      // pairwise-tree reduce: depth 3 on the gate critical path
      const f32x4* rp2 = &red[t & 1][mt * 64 + lane];   // wv stride = 256 f32x4
      f32x4 s01 = rp2[0]    + rp2[256];
      f32x4 s23 = rp2[512]  + rp2[768];
      f32x4 s45 = rp2[1024] + rp2[1280];
      f32x4 s67 = rp2[1536] + rp2[1792];
      f32x4 s = (s01 + s23) + (s45 + s67);
      // lane owns all 4 gates of (b = bg0+n, j = j0+mt*4+q): regs = i,f,g,o
      float gi = s.x + bias0, gf = s.y + bias1, gg = s.z + bias2, go = s.w + bias3;
      c_state = sigm(gf) * c_state + sigm(gi) * tanh_fast(gg);
      float h = sigm(go) * tanh_fast(c_state);

      // gather 4 q-values per batch to lanes<16 (2 shfl), fire tagged packet
      u32 hv  = (u32)__builtin_bit_cast(u16, (_Float16)h);
      u32 o16 = (u32)__shfl_xor((int)hv, 16);
      u32 pair = (hv & 0xffffu) | (o16 << 16);       // at even q: {h_q, h_q+1}
      u32 o32 = (u32)__shfl_xor((int)pair, 32);      // at q==0: {h2, h3}
      if (lane < 16) {
        u64 tg = (u64)(u32)(t + 1);
        u64 Apkt = (u64)pair | ((u64)(o32 & 0xffffu) << 32) | (tg << 48);
        u64 Bpkt = (u64)((o32 >> 16) & 0xffffu) | (tg << 16);
        u64* pp = pkt + (size_t)((t + 1) & 1) * 32768 + pwb;
        __hip_atomic_store(pp,     Apkt, __ATOMIC_RELAXED, __HIP_MEMORY_SCOPE_AGENT);
        __hip_atomic_store(pp + 1, Bpkt, __ATOMIC_RELAXED, __HIP_MEMORY_SCOPE_AGENT);
      }
      // fused out-projection partial (fire-and-forget)
      float p = h * wout;
      p += __shfl_xor(p, 16);
      p += __shfl_xor(p, 32);
      if (lane < 16)
        __hip_atomic_fetch_add(&part[((size_t)(t * 4 + g) * 64 + r) * 16 + lane], p,
                               __ATOMIC_RELAXED, __HIP_MEMORY_SCOPE_WORKGROUP);
    }
  }
}

// ---------- K4: out[b][t] = b_out + sum_r part[t][g][r][b&15] ----------
__global__ __launch_bounds__(256) void k_out(const float* __restrict__ part,
                                             const float* __restrict__ b_out,
                                             float* __restrict__ out) {
  int gi = blockIdx.x * 256 + threadIdx.x;      // 32768 threads
  int t = gi >> 6, b = gi & 63, g = b >> 4, b16 = b & 15;
  const float* p = part + ((size_t)(t * 4 + g) * 64) * 16 + b16;
  float s = b_out[0];
#pragma unroll 8
  for (int r = 0; r < 64; ++r) s += p[r * 16];
  out[(size_t)b * 512 + t] = s;
}

extern "C" void kernel_launch(void* const* d_in, const int* in_sizes, int n_in,
                              void* d_out, int out_size, void* d_ws, size_t ws_size,
                              hipStream_t stream) {
  const float* x    = (const float*)d_in[0];
  const float* W_ih = (const float*)d_in[1];
  const float* W_hh = (const float*)d_in[2];
  const float* b_ih = (const float*)d_in[3];
  const float* b_hh = (const float*)d_in[4];
  const float* Wout = (const float*)d_in[5];
  const float* bout = (const float*)d_in[6];
  float* out = (float*)d_out;

  unsigned char* ws = (unsigned char*)d_ws;
  u16* xT   = (u16*)(ws + WS_XT_OFF);
  u16* Wf   = (u16*)(ws + WS_WF_OFF);
  u64* pkt  = (u64*)(ws + WS_PK_OFF);
  float* part = (float*)(ws + WS_WF_OFF);       // reuses Wf region after load

  k_init<<<128, 256, 0, stream>>>((uint4*)pkt);
  k_xpose<<<dim3(8, 8, 64), 256, 0, stream>>>(x, xT);
  k_wfrag<<<3072, 256, 0, stream>>>(W_ih, W_hh, Wf);

  void* args[7] = {&xT, &Wf, &pkt, &b_ih, &b_hh, &Wout, &part};
  hipLaunchCooperativeKernel((const void*)k_lstm, dim3(256), dim3(512), args, 0, stream);

  k_out<<<128, 256, 0, stream>>>(part, bout, out);
}

// Round 13
// 2409.316 us; speedup vs baseline: 1.1387x; 1.1387x over previous
//
#include <hip/hip_runtime.h>
#include <cstddef>

// SimpleLSTM: B=64, D=512, T=512, H=1024, O=1 — fp16, tagged h-packets (r6 base,
// 1857.7us verified) + x-PREFETCH only.
// MODEL (r2-r10): time = 512 x serial coherence chain; legs & placement matter
// (r4/r6 wins); bytes off-chain free (r5); retry OVER-sampling poisons the
// publish service (r10: double-gen retry +52% — reverted). This round keeps the
// r6 protocol exactly and hides the one remaining off-protocol serial stall:
// the per-step cold xT read (~900 cyc HBM) consumed immediately by the x-MFMAs
// -> software-pipeline x by one step (registers only).
// ws layout (ends at 46,661,632):
//   [0, 32MB)            xT: f16 [T=512][B=64][D=512]
//   [32MB, +12.58MB)     Wf: f16 A-frags [r=64][ks=48][mt=4][lane=64][8]
//                        (reused after weight load as out-partials
//                         part[t=512][g=4][r=64][b16=16] f32 = 8MB, atomicAdd'd)
//   [46,137,344, +512KB) pkt[parity=2][g=4][r=64][mt=4][b=16] x 16B packets
//                        packet = {h0,h1,h2,tagA | h3,tagB,pad,pad} (2 u64)
//                        claim/ready ctrs overlay first ~1KB of parity-1 region
//                        (stale bits read as tag 0 != expected -> retry, safe).
#define WS_XT_OFF   0ull
#define WS_WF_OFF   33554432ull
#define WS_PK_OFF   46137344ull

typedef _Float16 f16x8 __attribute__((ext_vector_type(8)));
typedef float    f32x4 __attribute__((ext_vector_type(4)));
typedef unsigned short u16;
typedef unsigned int   u32;
typedef unsigned long long u64;

__device__ __forceinline__ u16 f2h(float f) {
  _Float16 h = (_Float16)f;                     // v_cvt_f16_f32, RNE
  return __builtin_bit_cast(u16, h);
}
// Fast gate math: v_exp + v_rcp. Robust at extremes.
__device__ __forceinline__ float sigm(float x) {
  return __builtin_amdgcn_rcpf(1.0f + __expf(-x));
}
__device__ __forceinline__ float tanh_fast(float x) {
  return 1.0f - 2.0f * __builtin_amdgcn_rcpf(__expf(2.0f * x) + 1.0f);
}

// ---------- K0: zero packet region (tags=0 == step-0 expectation, h=0) ----------
__global__ __launch_bounds__(256) void k_init(uint4* pkt16) {
  int t = blockIdx.x * 256 + threadIdx.x;       // 32768 threads x 16B = 512KB exact
  pkt16[t] = uint4{0u, 0u, 0u, 0u};
}

// ---------- K1: x (B,D,T) f32 -> xT[t][b][d] f16 ----------
__global__ __launch_bounds__(256) void k_xpose(const float* __restrict__ x,
                                               u16* __restrict__ xT) {
  __shared__ float lds[64][65];
  const int d0 = blockIdx.x * 64, t0 = blockIdx.y * 64, b = blockIdx.z;
  const int tid = threadIdx.x;
  const int tt = tid & 63, dr = tid >> 6;
  const float* xp = x + ((size_t)b * 512 + d0) * 512 + t0 + tt;
#pragma unroll
  for (int i = 0; i < 16; ++i) {
    int dd = i * 4 + dr;
    lds[dd][tt] = xp[(size_t)dd * 512];
  }
  __syncthreads();
  const int dp = tid & 31, rr = tid >> 5;
#pragma unroll
  for (int i = 0; i < 8; ++i) {
    int tt2 = i * 8 + rr;
    u32 lo = f2h(lds[dp * 2][tt2]);
    u32 hi = f2h(lds[dp * 2 + 1][tt2]);
    *(u32*)(xT + ((size_t)(t0 + tt2) * 64 + b) * 512 + d0 + dp * 2) = lo | (hi << 16);
  }
}

// ---------- K2: pack [W_ih | W_hh] rows into per-lane MFMA A-fragments (f16) ----------
// chunk c = (r*48 + ks)*4 + mt ; within-tile row m: gate=m&3, j=r*16+mt*4+(m>>2)
__global__ __launch_bounds__(256) void k_wfrag(const float* __restrict__ W_ih,
                                               const float* __restrict__ W_hh,
                                               u16* __restrict__ Wf) {
  int g = blockIdx.x * 256 + threadIdx.x;       // 786432 threads
  int lane = g & 63;
  int c  = g >> 6;                              // [0, 12288)
  int mt = c & 3;
  int cc = c >> 2;
  int ks = cc % 48;
  int r  = cc / 48;
  int m = lane & 15, q = lane >> 4;
  int gate = m & 3;
  int j = r * 16 + mt * 4 + (m >> 2);
  int row = gate * 1024 + j;
  const float* src = (ks < 16) ? (W_ih + (size_t)row * 512 + ks * 32 + q * 8)
                               : (W_hh + (size_t)row * 1024 + (ks - 16) * 32 + q * 8);
  union { u16 s[8]; uint4 v; } U;
#pragma unroll
  for (int i = 0; i < 8; ++i) U.s[i] = f2h(src[i]);
  *(uint4*)(Wf + ((size_t)c * 64 + lane) * 8) = U.v;
}

// ---------- K3: persistent cooperative recurrence ----------
// grid 256 = 4 groups x 64 blocks; block 512 = 8 waves; 1 block/CU.
// XCD CLAIM (r4-verified): g = xcd>>1, r = (xcd&1)|(slot<<1) — each group on
// 2 XCDs (FETCH halved, counter-confirmed).
// PACKETS (r6-verified): producer reducer-wave mt gathers 4 q-values per batch
// (2 shfl_xor) and fires TWO u64 agent stores per lane<16:
// {h0,h1,h2,tagA | h3,tagB} at pkt[(t+1)&1][g][r][mt][b]. Consumer wave w
// retry-loads its 16 u64, validates embedded tags == t; poll IS the data load.
// Retry is SINGLE-generation (r10 lesson: over-sampling delays the publish).
__global__ __launch_bounds__(512, 2) void k_lstm(
    const u16* __restrict__ xT, const u16* __restrict__ Wf,
    u64* pkt,
    const float* __restrict__ b_ih, const float* __restrict__ b_hh,
    const float* __restrict__ W_out, float* __restrict__ part) {
  __shared__ f32x4 red[2][8 * 4 * 64];    // [parity][wave][mt][lane], 64 KB
  __shared__ u32 sh_as;                   // claimed (xcd<<8)|slot
  const int tid = threadIdx.x;
  const int w = tid >> 6, lane = tid & 63;

  // claim/ready overlay in parity-1 region (stale bits read as tag 0 -> safe)
  u32* cc = (u32*)(pkt + 32768);

  if (tid == 0) {
    u32 xcc;
    asm volatile("s_getreg_b32 %0, hwreg(HW_REG_XCC_ID)" : "=s"(xcc));
    xcc &= 7u;
    u32 sel = 0u, slot = 0u;
    for (int i = 0; i < 8; ++i) {
      u32 x = (xcc + (u32)i) & 7u;
      u32 s = __hip_atomic_fetch_add(cc + x * 32, 1u,
                                     __ATOMIC_RELAXED, __HIP_MEMORY_SCOPE_AGENT);
      if (s < 32u) { sel = x; slot = s; break; }
    }
    sh_as = (sel << 8) | slot;
  }
  __syncthreads();
  const u32 as = sh_as;
  const int g = (int)((as >> 8) >> 1);
  const int r = (int)(((as >> 8) & 1u) | ((as & 255u) << 1));
  const int bg0 = g * 16, j0 = r * 16;
  const int n = lane & 15, q = lane >> 4;

  // Step-invariant weights -> registers
  f16x8 wfr[6][4];
#pragma unroll
  for (int kl = 0; kl < 6; ++kl) {
    int ks = (kl < 2) ? (2 * w + kl) : (16 + 4 * w + (kl - 2));
#pragma unroll
    for (int mt = 0; mt < 4; ++mt) {
      size_t c = ((size_t)r * 48 + ks) * 4 + mt;
      wfr[kl][mt] = *(const f16x8*)(Wf + (c * 64 + lane) * 8);
    }
  }

  float bias0 = 0.f, bias1 = 0.f, bias2 = 0.f, bias3 = 0.f, wout = 0.f;
  if (w < 4) {
    int j = j0 + w * 4 + q;
    bias0 = b_ih[j]        + b_hh[j];
    bias1 = b_ih[1024 + j] + b_hh[1024 + j];
    bias2 = b_ih[2048 + j] + b_hh[2048 + j];
    bias3 = b_ih[3072 + j] + b_hh[3072 + j];
    wout  = W_out[j];
  }

  // Consumer packet bases (u64 units within a parity), layout [g][p][mt][b]:
  // idx = (((g*64 + p)*4 + mt')*16 + n)*2 ; p=(4w+kl)*2+(q>>1), mt'=(q&1)*2.
  size_t cb[4];
#pragma unroll
  for (int kl = 0; kl < 4; ++kl) {
    int p = (4 * w + kl) * 2 + (q >> 1);
    cb[kl] = ((((size_t)g * 64 + p) * 4 + (size_t)((q & 1) * 2)) * 16 + n) * 2;
  }
  // Producer packet base (w<4, lane<16): block r, quarter mt=w, batch b=lane
  const size_t pwb = ((((size_t)g * 64 + r) * 4 + w) * 16 + (lane & 15)) * 2;

  // One-time grid barrier: all Wf loads done before part[] overwrites Wf.
  __syncthreads();                        // drains vmcnt -> wfr in regs
  if (tid == 0) {
    __hip_atomic_fetch_add(cc + 256, 1u, __ATOMIC_RELAXED, __HIP_MEMORY_SCOPE_AGENT);
    while (__hip_atomic_load(cc + 256, __ATOMIC_RELAXED, __HIP_MEMORY_SCOPE_AGENT) < 256u)
      __builtin_amdgcn_s_sleep(8);
  }
  __syncthreads();
  // zero own out-partial slice part[t=tid][g][r][0..16)
  {
    f32x4 z = {0.f, 0.f, 0.f, 0.f};
    f32x4* p4 = (f32x4*)&part[((size_t)(tid * 4 + g) * 64 + r) * 16];
    p4[0] = z; p4[1] = z; p4[2] = z; p4[3] = z;
  }
  __syncthreads();                        // drain zero stores before any atomicAdd
  asm volatile("" ::: "memory");

  float c_state = 0.f;
  const f32x4 zero = {0.f, 0.f, 0.f, 0.f};

  // x-prefetch registers: step-0 x loaded in prologue (one-time serial cost)
  const int xoff = (bg0 + n) * 512 + q * 8;
  f16x8 xpf0 = *(const f16x8*)(xT + xoff + (2 * w + 0) * 32);
  f16x8 xpf1 = *(const f16x8*)(xT + xoff + (2 * w + 1) * 32);

  for (int t = 0; t < 512; ++t) {
    // consume prefetched x (loads issued a full step ago -> vmcnt wait ~0)
    f16x8 bfr[6];
    bfr[0] = xpf0;
    bfr[1] = xpf1;
    // issue prefetch for t+1 (wraps to 0 at the end: valid address, unused)
    {
      const u16* xtn = xT + (size_t)((t + 1) & 511) * 32768;
      xpf0 = *(const f16x8*)(xtn + xoff + (2 * w + 0) * 32);
      xpf1 = *(const f16x8*)(xtn + xoff + (2 * w + 1) * 32);
    }

    const u64* pb = pkt + (size_t)(t & 1) * 32768;
    const u32 et = (u32)t;
    u64 A[16];
    // initial packet sample issued BEFORE the x-MFMAs: its RTT overlaps them
#pragma unroll
    for (int kl = 0; kl < 4; ++kl) {
      const u64* p = pb + cb[kl];
      A[kl*4+0] = __hip_atomic_load(p,      __ATOMIC_RELAXED, __HIP_MEMORY_SCOPE_AGENT);
      A[kl*4+1] = __hip_atomic_load(p + 1,  __ATOMIC_RELAXED, __HIP_MEMORY_SCOPE_AGENT);
      A[kl*4+2] = __hip_atomic_load(p + 32, __ATOMIC_RELAXED, __HIP_MEMORY_SCOPE_AGENT);
      A[kl*4+3] = __hip_atomic_load(p + 33, __ATOMIC_RELAXED, __HIP_MEMORY_SCOPE_AGENT);
    }

    // x-part MFMAs (x already in regs; issue-cost only, overlap sample RTT)
    f32x4 acc[4];
#pragma unroll
    for (int mt = 0; mt < 4; ++mt)
      acc[mt] = __builtin_amdgcn_mfma_f32_16x16x32_f16(wfr[0][mt], bfr[0], zero, 0, 0, 0);
#pragma unroll
    for (int mt = 0; mt < 4; ++mt)
      acc[mt] = __builtin_amdgcn_mfma_f32_16x16x32_f16(wfr[1][mt], bfr[1], acc[mt], 0, 0, 0);
#pragma unroll
    for (int mt = 0; mt < 4; ++mt) asm volatile("" : "+v"(acc[mt]));

    // single-generation validated retry (r6 semantics): check, reissue if stale
    for (;;) {
      bool ok = true;
#pragma unroll
      for (int kl = 0; kl < 4; ++kl) {
        ok = ok & ((u32)(A[kl*4+0] >> 48) == et)
                & (((u32)(A[kl*4+1] >> 16) & 0xffffu) == et)
                & ((u32)(A[kl*4+2] >> 48) == et)
                & (((u32)(A[kl*4+3] >> 16) & 0xffffu) == et);
      }
      if (__all((int)ok)) break;
#pragma unroll
      for (int kl = 0; kl < 4; ++kl) {
        const u64* p = pb + cb[kl];
        A[kl*4+0] = __hip_atomic_load(p,      __ATOMIC_RELAXED, __HIP_MEMORY_SCOPE_AGENT);
        A[kl*4+1] = __hip_atomic_load(p + 1,  __ATOMIC_RELAXED, __HIP_MEMORY_SCOPE_AGENT);
        A[kl*4+2] = __hip_atomic_load(p + 32, __ATOMIC_RELAXED, __HIP_MEMORY_SCOPE_AGENT);
        A[kl*4+3] = __hip_atomic_load(p + 33, __ATOMIC_RELAXED, __HIP_MEMORY_SCOPE_AGENT);
      }
    }
    asm volatile("" ::: "memory");

    // assemble h fragments from validated packets
#pragma unroll
    for (int kl = 0; kl < 4; ++kl) {
      union { u32 u[4]; f16x8 v; } Bu;
      Bu.u[0] = (u32)A[kl*4+0];
      Bu.u[1] = ((u32)(A[kl*4+0] >> 32) & 0xffffu) | (((u32)A[kl*4+1] & 0xffffu) << 16);
      Bu.u[2] = (u32)A[kl*4+2];
      Bu.u[3] = ((u32)(A[kl*4+2] >> 32) & 0xffffu) | (((u32)A[kl*4+3] & 0xffffu) << 16);
      bfr[kl + 2] = Bu.v;
    }

#pragma unroll
    for (int kl = 2; kl < 6; ++kl)
#pragma unroll
      for (int mt = 0; mt < 4; ++mt)
        acc[mt] = __builtin_amdgcn_mfma_f32_16x16x32_f16(wfr[kl][mt], bfr[kl], acc[mt], 0, 0, 0);

#pragma unroll
    for (int mt = 0; mt < 4; ++mt)
      red[t & 1][(w * 4 + mt) * 64 + lane] = acc[mt];
    __syncthreads();                      // the ONLY barrier per step

    if (w < 4) {
      const int mt = w;
      // pairwise-tree reduce: depth 3 on the gate critical path
      const f32x4* rp2 = &red[t & 1][mt * 64 + lane];   // wv stride = 256 f32x4
      f32x4 s01 = rp2[0]    + rp2[256];
      f32x4 s23 = rp2[512]  + rp2[768];
      f32x4 s45 = rp2[1024] + rp2[1280];
      f32x4 s67 = rp2[1536] + rp2[1792];
      f32x4 s = (s01 + s23) + (s45 + s67);
      // lane owns all 4 gates of (b = bg0+n, j = j0+mt*4+q): regs = i,f,g,o
      float gi = s.x + bias0, gf = s.y + bias1, gg = s.z + bias2, go = s.w + bias3;
      c_state = sigm(gf) * c_state + sigm(gi) * tanh_fast(gg);
      float h = sigm(go) * tanh_fast(c_state);

      // gather 4 q-values per batch to lanes<16 (2 shfl), fire tagged packet
      u32 hv  = (u32)__builtin_bit_cast(u16, (_Float16)h);
      u32 o16 = (u32)__shfl_xor((int)hv, 16);
      u32 pair = (hv & 0xffffu) | (o16 << 16);       // at even q: {h_q, h_q+1}
      u32 o32 = (u32)__shfl_xor((int)pair, 32);      // at q==0: {h2, h3}
      if (lane < 16) {
        u64 tg = (u64)(u32)(t + 1);
        u64 Apkt = (u64)pair | ((u64)(o32 & 0xffffu) << 32) | (tg << 48);
        u64 Bpkt = (u64)((o32 >> 16) & 0xffffu) | (tg << 16);
        u64* pp = pkt + (size_t)((t + 1) & 1) * 32768 + pwb;
        __hip_atomic_store(pp,     Apkt, __ATOMIC_RELAXED, __HIP_MEMORY_SCOPE_AGENT);
        __hip_atomic_store(pp + 1, Bpkt, __ATOMIC_RELAXED, __HIP_MEMORY_SCOPE_AGENT);
      }
      // fused out-projection partial (fire-and-forget)
      float p = h * wout;
      p += __shfl_xor(p, 16);
      p += __shfl_xor(p, 32);
      if (lane < 16)
        __hip_atomic_fetch_add(&part[((size_t)(t * 4 + g) * 64 + r) * 16 + lane], p,
                               __ATOMIC_RELAXED, __HIP_MEMORY_SCOPE_WORKGROUP);
    }
  }
}

// ---------- K4: out[b][t] = b_out + sum_r part[t][g][r][b&15] ----------
__global__ __launch_bounds__(256) void k_out(const float* __restrict__ part,
                                             const float* __restrict__ b_out,
                                             float* __restrict__ out) {
  int gi = blockIdx.x * 256 + threadIdx.x;      // 32768 threads
  int t = gi >> 6, b = gi & 63, g = b >> 4, b16 = b & 15;
  const float* p = part + ((size_t)(t * 4 + g) * 64) * 16 + b16;
  float s = b_out[0];
#pragma unroll 8
  for (int r = 0; r < 64; ++r) s += p[r * 16];
  out[(size_t)b * 512 + t] = s;
}

extern "C" void kernel_launch(void* const* d_in, const int* in_sizes, int n_in,
                              void* d_out, int out_size, void* d_ws, size_t ws_size,
                              hipStream_t stream) {
  const float* x    = (const float*)d_in[0];
  const float* W_ih = (const float*)d_in[1];
  const float* W_hh = (const float*)d_in[2];
  const float* b_ih = (const float*)d_in[3];
  const float* b_hh = (const float*)d_in[4];
  const float* Wout = (const float*)d_in[5];
  const float* bout = (const float*)d_in[6];
  float* out = (float*)d_out;

  unsigned char* ws = (unsigned char*)d_ws;
  u16* xT   = (u16*)(ws + WS_XT_OFF);
  u16* Wf   = (u16*)(ws + WS_WF_OFF);
  u64* pkt  = (u64*)(ws + WS_PK_OFF);
  float* part = (float*)(ws + WS_WF_OFF);       // reuses Wf region after load

  k_init<<<128, 256, 0, stream>>>((uint4*)pkt);
  k_xpose<<<dim3(8, 8, 64), 256, 0, stream>>>(x, xT);
  k_wfrag<<<3072, 256, 0, stream>>>(W_ih, W_hh, Wf);

  void* args[7] = {&xT, &Wf, &pkt, &b_ih, &b_hh, &Wout, &part};
  hipLaunchCooperativeKernel((const void*)k_lstm, dim3(256), dim3(512), args, 0, stream);

  k_out<<<128, 256, 0, stream>>>(part, bout, out);
}